// Round 1
// baseline (6763.035 us; speedup 1.0000x reference)
//
#include <hip/hip_runtime.h>

// ---------------- problem constants ----------------
#define TPB   256
#define NWG   256
#define SEQL  200
#define BATCH 64
#define EDIM  300
#define HDIM  512
#define ODIM  5

// ---------------- LDS layout (float offsets) ----------------
// h/emb staging rows use stride 516 floats: 516 % 32 == 4 -> bank-spread for
// the (r,q) lane pattern, and 516 % 4 == 0 -> 16B-aligned float4 rows.
#define HSTR      516
#define LDSF_H    0                       // 64 x 516 (time-shared: emb -> h -> gates)
#define LDSF_WHH  (64 * HSTR)             // 8 x 516  (W_hh rows, resident whole kernel)
#define WIHSTR    308                     // 308 % 32 == 20 -> lanes r=0..7 hit distinct bank groups
#define LDSF_WIH  (LDSF_WHH + 8 * HSTR)   // 8 x 308  (W_ih rows, resident whole kernel)
#define GSTR      68                      // gate-exchange stride (8 x 68, lives in h region)
#define LDS_FLOATS (LDSF_WIH + 8 * WIHSTR)   // 39616 floats
#define LDS_BYTES  (LDS_FLOATS * 4)          // 158464 B < 160 KiB

__device__ __forceinline__ float fast_sigmoid(float x) {
    return 1.0f / (1.0f + __expf(-x));
}
__device__ __forceinline__ float fast_tanh(float x) {
    // 2*sigmoid(2x)-1 ; saturates correctly at +-inf via __expf
    return 2.0f / (1.0f + __expf(-2.0f * x)) - 1.0f;
}

// Persistent LSTM kernel: 256 wgs x 256 threads, 1 wg/CU (forced by LDS).
// wg owns hidden indices {2*wg, 2*wg+1} for all 4 gates, all 64 batch rows.
// One device-wide barrier per timestep (monotonic counter in d_ws).
extern "C" __global__ void __launch_bounds__(TPB, 1)
lstm_persist(const int* __restrict__ x, const float* __restrict__ emb,
             const float* __restrict__ W_ih, const float* __restrict__ W_hh,
             const float* __restrict__ b_ih, const float* __restrict__ b_hh,
             float* __restrict__ h_glob,      // [2][64][512] double-buffered
             unsigned int* __restrict__ cnt)  // barrier counter (memset 0 per launch)
{
    extern __shared__ float lds[];
    const int tid = threadIdx.x;
    const int wg  = blockIdx.x;

    // ---- stage W_hh rows (8 x 512) and W_ih rows (8 x 300) into LDS, once ----
    for (int i = tid; i < 8 * HDIM; i += TPB) {
        int r = i >> 9, k = i & (HDIM - 1);
        int R = ((r >> 1) << 9) + 2 * wg + (r & 1);     // gate*512 + hidden idx
        lds[LDSF_WHH + r * HSTR + k] = W_hh[(size_t)R * HDIM + k];
    }
    for (int i = tid; i < 8 * EDIM; i += TPB) {
        int r = i / EDIM, e = i - r * EDIM;
        int R = ((r >> 1) << 9) + 2 * wg + (r & 1);
        lds[LDSF_WIH + r * WIHSTR + e] = W_ih[(size_t)R * EDIM + e];
    }

    // thread roles: (r = gate-row 0..7, q = b-pair 0..31) -> 2 accumulators
    const int r  = tid & 7;
    const int q  = tid >> 3;
    const int b0 = 2 * q, b1 = 2 * q + 1;
    const int Rr = ((r >> 1) << 9) + 2 * wg + (r & 1);
    const float bias_r = b_ih[Rr] + b_hh[Rr];

    // cell-update role: threads 0..127 own cell (hi, cb)
    const bool cell = (tid < 128);
    const int hi = (tid >> 6) & 1;
    const int cb = tid & 63;
    float c_reg = 0.0f;

    const float4* wiha = (const float4*)&lds[LDSF_WIH + r * WIHSTR];
    const float4* whha = (const float4*)&lds[LDSF_WHH + r * HSTR];
    const float4* hr0  = (const float4*)&lds[LDSF_H + b0 * HSTR];
    const float4* hr1  = (const float4*)&lds[LDSF_H + b1 * HSTR];

    __syncthreads();   // weights staged

    for (int s = 0; s < SEQL; s++) {
        const unsigned long long* hsrc =
            (const unsigned long long*)(h_glob + ((s + 1) & 1) * (BATCH * HDIM));
        unsigned int* hdst = (unsigned int*)(h_glob + (s & 1) * (BATCH * HDIM));

        // ---- (1) issue previous-h loads early (agent scope = coherent across XCDs);
        //         latency hides under emb staging + pass A ----
        unsigned long long hreg[64];
        if (s) {
#pragma unroll
            for (int j = 0; j < 64; j++)
                hreg[j] = __hip_atomic_load(hsrc + tid + TPB * j,
                                            __ATOMIC_RELAXED, __HIP_MEMORY_SCOPE_AGENT);
        }

        // ---- (2) stage embedding rows for step s into h region ----
        for (int i = tid; i < BATCH * 75; i += TPB) {   // 75 float4 per 300-float row
            int b = i / 75, j = i - b * 75;
            int row = x[b * SEQL + s];
            float4 v = ((const float4*)(emb + (size_t)row * EDIM))[j];
            *(float4*)&lds[LDSF_H + b * HSTR + 4 * j] = v;
        }
        __syncthreads();

        // ---- (3) pass A: input projection (K = 300) ----
        float acc0 = bias_r, acc1 = bias_r;
#pragma unroll 5
        for (int t2 = 0; t2 < 75; t2++) {
            float4 w = wiha[t2], a = hr0[t2], b = hr1[t2];
            acc0 = fmaf(w.x, a.x, acc0); acc0 = fmaf(w.y, a.y, acc0);
            acc0 = fmaf(w.z, a.z, acc0); acc0 = fmaf(w.w, a.w, acc0);
            acc1 = fmaf(w.x, b.x, acc1); acc1 = fmaf(w.y, b.y, acc1);
            acc1 = fmaf(w.z, b.z, acc1); acc1 = fmaf(w.w, b.w, acc1);
        }
        __syncthreads();   // emb region free

        // ---- (4) pass B: recurrent projection (K = 512) ----
        if (s) {
#pragma unroll
            for (int j = 0; j < 64; j++) {              // h -> LDS (transposed stride)
                int idx = tid + TPB * j;
                int b = idx >> 8, kk = idx & 255;
                *(unsigned long long*)&lds[LDSF_H + b * HSTR + 2 * kk] = hreg[j];
            }
            __syncthreads();
#pragma unroll 4
            for (int t2 = 0; t2 < 128; t2++) {
                float4 w = whha[t2], a = hr0[t2], b = hr1[t2];
                acc0 = fmaf(w.x, a.x, acc0); acc0 = fmaf(w.y, a.y, acc0);
                acc0 = fmaf(w.z, a.z, acc0); acc0 = fmaf(w.w, a.w, acc0);
                acc1 = fmaf(w.x, b.x, acc1); acc1 = fmaf(w.y, b.y, acc1);
                acc1 = fmaf(w.z, b.z, acc1); acc1 = fmaf(w.w, b.w, acc1);
            }
            __syncthreads();   // h region free
        }

        // ---- (5) gate exchange + local cell update ----
        lds[r * GSTR + b0] = acc0;
        lds[r * GSTR + b1] = acc1;
        __syncthreads();
        if (cell) {
            float gi = lds[(0 + hi) * GSTR + cb];
            float gf = lds[(2 + hi) * GSTR + cb];
            float gg = lds[(4 + hi) * GSTR + cb];
            float go = lds[(6 + hi) * GSTR + cb];
            float iv = fast_sigmoid(gi);
            float fv = fast_sigmoid(gf);
            float gv = fast_tanh(gg);
            float ov = fast_sigmoid(go);
            c_reg = fv * c_reg + iv * gv;
            float hv = ov * fast_tanh(c_reg);
            // coherent store of h[cb][2*wg+hi]
            __hip_atomic_store(hdst + cb * HDIM + 2 * wg + hi, __float_as_uint(hv),
                               __ATOMIC_RELAXED, __HIP_MEMORY_SCOPE_AGENT);
        }
        __syncthreads();   // drains all vmem (compiler emits vmcnt(0) before s_barrier)

        // ---- (6) device-wide barrier: monotonic counter ----
        if (tid == 0) {
            __hip_atomic_fetch_add(cnt, 1u, __ATOMIC_RELEASE, __HIP_MEMORY_SCOPE_AGENT);
            unsigned int target = (unsigned)NWG * (unsigned)(s + 1);
            while (__hip_atomic_load(cnt, __ATOMIC_RELAXED, __HIP_MEMORY_SCOPE_AGENT) < target)
                __builtin_amdgcn_s_sleep(1);
            __threadfence();
        }
        __syncthreads();
    }
}

// FC head + softmax: logits[64][5] = h_final @ W_fc^T + b_fc -> softmax
extern "C" __global__ void __launch_bounds__(320)
lstm_epilogue(const float* __restrict__ h, const float* __restrict__ W_fc,
              const float* __restrict__ b_fc, float* __restrict__ out)
{
    __shared__ float sl[ODIM * BATCH];
    const int t = threadIdx.x;                 // 320 = 5 waves
    {
        int o = t / BATCH, b = t - o * BATCH;  // o in [0,5), b in [0,64)
        float acc = b_fc[o];
        const float4* hv = (const float4*)(h + b * HDIM);
        const float4* wv = (const float4*)(W_fc + o * HDIM);
#pragma unroll 8
        for (int j = 0; j < HDIM / 4; j++) {
            float4 a = hv[j], w = wv[j];
            acc = fmaf(a.x, w.x, acc); acc = fmaf(a.y, w.y, acc);
            acc = fmaf(a.z, w.z, acc); acc = fmaf(a.w, w.w, acc);
        }
        sl[o * BATCH + b] = acc;
    }
    __syncthreads();
    if (t < BATCH) {
        float l0 = sl[t], l1 = sl[BATCH + t], l2 = sl[2 * BATCH + t];
        float l3 = sl[3 * BATCH + t], l4 = sl[4 * BATCH + t];
        float m = fmaxf(fmaxf(fmaxf(l0, l1), fmaxf(l2, l3)), l4);
        float e0 = __expf(l0 - m), e1 = __expf(l1 - m), e2 = __expf(l2 - m);
        float e3 = __expf(l3 - m), e4 = __expf(l4 - m);
        float inv = 1.0f / (e0 + e1 + e2 + e3 + e4);
        out[t * ODIM + 0] = e0 * inv;
        out[t * ODIM + 1] = e1 * inv;
        out[t * ODIM + 2] = e2 * inv;
        out[t * ODIM + 3] = e3 * inv;
        out[t * ODIM + 4] = e4 * inv;
    }
}

extern "C" void kernel_launch(void* const* d_in, const int* in_sizes, int n_in,
                              void* d_out, int out_size, void* d_ws, size_t ws_size,
                              hipStream_t stream)
{
    const int*   x    = (const int*)d_in[0];
    const float* emb  = (const float*)d_in[1];
    const float* W_ih = (const float*)d_in[2];
    const float* W_hh = (const float*)d_in[3];
    const float* b_ih = (const float*)d_in[4];
    const float* b_hh = (const float*)d_in[5];
    const float* W_fc = (const float*)d_in[6];
    const float* b_fc = (const float*)d_in[7];
    float* out = (float*)d_out;

    // workspace: [0 .. 256KiB) h double buffer, then barrier counter
    float* h_glob = (float*)d_ws;
    unsigned int* cnt = (unsigned int*)((char*)d_ws + 2 * BATCH * HDIM * sizeof(float));

    hipMemsetAsync(cnt, 0, sizeof(unsigned int), stream);   // reset barrier each launch

    // >64KB dynamic LDS needs opt-in (idempotent, not a stream op -> capture-safe)
    hipFuncSetAttribute((const void*)lstm_persist,
                        hipFuncAttributeMaxDynamicSharedMemorySize, LDS_BYTES);

    lstm_persist<<<NWG, TPB, LDS_BYTES, stream>>>(x, emb, W_ih, W_hh, b_ih, b_hh,
                                                  h_glob, cnt);
    // final h lives in buffer (SEQL-1)&1 == 1
    lstm_epilogue<<<1, 320, 0, stream>>>(h_glob + BATCH * HDIM, W_fc, b_fc, out);
}

// Round 3
// 4456.916 us; speedup vs baseline: 1.5174x; 1.5174x over previous
//
#include <hip/hip_runtime.h>

// ---------------- problem constants ----------------
#define TPB   256
#define NWG   256
#define SEQL  200
#define BATCH 64
#define EDIM  300
#define HDIM  512
#define ODIM  5
#define NROW  (4*HDIM)   // 2048 gate rows

// ---------------- persist-kernel LDS layout (float offsets) ----------------
#define HSTR      516
#define LDSF_H    0                       // 64 x 516 (time-shared: emb -> h -> gates)
#define LDSF_WHH  (64 * HSTR)             // 8 x 516  (W_hh rows, resident)
#define WIHSTR    308
#define LDSF_WIH  (LDSF_WHH + 8 * HSTR)   // 8 x 308  (W_ih rows, fallback only)
#define GSTR      68
#define LDS_FLOATS (LDSF_WIH + 8 * WIHSTR)   // 39616 floats
#define LDS_BYTES  (LDS_FLOATS * 4)          // 158464 B < 160 KiB

// ---------------- precompute-kernel LDS ----------------
#define ESTR 308
#define PRE_LDS_BYTES (BATCH * ESTR * 4)     // 78848 B

// ---------------- workspace layout ----------------
#define WS_H_FLOATS   (2 * BATCH * HDIM)                    // 65536 floats (256 KiB)
#define WS_FLAGS_OFF  ((size_t)WS_H_FLOATS * 4)             // byte offset
#define WS_FLAGS_BYTES 1024                                 // 256 uint flags
#define WS_GATES_OFF  (WS_FLAGS_OFF + WS_FLAGS_BYTES)
#define GATES_FLOATS  ((size_t)SEQL * NROW * BATCH)         // 26,214,400 (104.9 MB)
#define WS_NEED       (WS_GATES_OFF + GATES_FLOATS * 4)

__device__ __forceinline__ float fast_sigmoid(float x) {
    return 1.0f / (1.0f + __expf(-x));
}
__device__ __forceinline__ float fast_tanh(float x) {
    return 2.0f / (1.0f + __expf(-2.0f * x)) - 1.0f;
}

// ============================================================================
// Precompute kernel: gates_in[s][row][b] = (x_s @ W_ih^T)[b][row]  (no bias)
// grid = SEQL*8 wgs: wg = (step s, row-block rb of 256 rows). 8x8 register
// tile per thread; emb rows staged in LDS (2-addr broadcast reads -> free);
// W_ih streamed from L2 (2.4 MB, XCD-resident).
// ============================================================================
extern "C" __global__ void __launch_bounds__(256, 1)
lstm_pre(const int* __restrict__ x, const float* __restrict__ emb,
         const float* __restrict__ W_ih, float* __restrict__ gates)
{
    extern __shared__ float embs[];
    const int tid = threadIdx.x;
    const int s   = blockIdx.x >> 3;
    const int rb  = blockIdx.x & 7;

    for (int i = tid; i < BATCH * 75; i += 256) {
        int b = i / 75, j = i - b * 75;
        int row = x[b * SEQL + s];
        float4 v = ((const float4*)(emb + (size_t)row * EDIM))[j];
        *(float4*)&embs[b * ESTR + 4 * j] = v;
    }
    __syncthreads();

    const int bi = tid >> 5;      // 0..7  (batch group of 8)
    const int ri = tid & 31;      // 0..31 (row group of 8)
    const int row0 = rb * 256 + ri * 8;
    const float* wp = W_ih + (size_t)row0 * EDIM;

    float acc[8][8];
#pragma unroll
    for (int a = 0; a < 8; a++)
#pragma unroll
        for (int b = 0; b < 8; b++) acc[a][b] = 0.0f;

    for (int t2 = 0; t2 < 75; t2++) {
        float4 w[8], e[8];
#pragma unroll
        for (int rr = 0; rr < 8; rr++)
            w[rr] = *(const float4*)(wp + rr * EDIM + 4 * t2);
#pragma unroll
        for (int bb = 0; bb < 8; bb++)
            e[bb] = *(const float4*)&embs[(bi * 8 + bb) * ESTR + 4 * t2];
#pragma unroll
        for (int rr = 0; rr < 8; rr++)
#pragma unroll
            for (int bb = 0; bb < 8; bb++) {
                acc[rr][bb] = fmaf(w[rr].x, e[bb].x, acc[rr][bb]);
                acc[rr][bb] = fmaf(w[rr].y, e[bb].y, acc[rr][bb]);
                acc[rr][bb] = fmaf(w[rr].z, e[bb].z, acc[rr][bb]);
                acc[rr][bb] = fmaf(w[rr].w, e[bb].w, acc[rr][bb]);
            }
    }
#pragma unroll
    for (int rr = 0; rr < 8; rr++) {
        float* dst = gates + ((size_t)s * NROW + row0 + rr) * BATCH + bi * 8;
        *(float4*)dst       = make_float4(acc[rr][0], acc[rr][1], acc[rr][2], acc[rr][3]);
        *(float4*)(dst + 4) = make_float4(acc[rr][4], acc[rr][5], acc[rr][6], acc[rr][7]);
    }
}

// ============================================================================
// Persistent LSTM kernel: 256 wgs x 256 threads, 1 wg/CU (forced by LDS).
// Flag-array device barrier (1 release store / wg, vector polls).
// gates != nullptr -> input projection precomputed; else in-loop pass A.
// ============================================================================
extern "C" __global__ void __launch_bounds__(TPB, 1)
lstm_persist(const int* __restrict__ x, const float* __restrict__ emb,
             const float* __restrict__ W_ih, const float* __restrict__ W_hh,
             const float* __restrict__ b_ih, const float* __restrict__ b_hh,
             const float* __restrict__ gates,   // may be null
             float* __restrict__ h_glob,        // [2][64][512]
             unsigned int* __restrict__ flags)  // [256], memset 0 per launch
{
    extern __shared__ float lds[];
    const int tid = threadIdx.x;
    const int wg  = blockIdx.x;
    const bool pre = (gates != nullptr);

    // ---- stage W_hh rows (8 x 512); W_ih rows only for fallback ----
    for (int i = tid; i < 8 * HDIM; i += TPB) {
        int r = i >> 9, k = i & (HDIM - 1);
        int R = ((r >> 1) << 9) + 2 * wg + (r & 1);
        lds[LDSF_WHH + r * HSTR + k] = W_hh[(size_t)R * HDIM + k];
    }
    if (!pre) {
        for (int i = tid; i < 8 * EDIM; i += TPB) {
            int r = i / EDIM, e = i - r * EDIM;
            int R = ((r >> 1) << 9) + 2 * wg + (r & 1);
            lds[LDSF_WIH + r * WIHSTR + e] = W_ih[(size_t)R * EDIM + e];
        }
    }

    const int r  = tid & 7;
    const int q  = tid >> 3;
    const int b0 = 2 * q, b1 = 2 * q + 1;
    const int Rr = ((r >> 1) << 9) + 2 * wg + (r & 1);
    const float bias_r = b_ih[Rr] + b_hh[Rr];

    const bool cell = (tid < 128);
    const int hi = (tid >> 6) & 1;
    const int cb = tid & 63;
    float c_reg = 0.0f;

    const float4* wiha = (const float4*)&lds[LDSF_WIH + r * WIHSTR];
    const float4* whha = (const float4*)&lds[LDSF_WHH + r * HSTR];
    const float4* hr0  = (const float4*)&lds[LDSF_H + b0 * HSTR];
    const float4* hr1  = (const float4*)&lds[LDSF_H + b1 * HSTR];

    __syncthreads();

    for (int s = 0; s < SEQL; s++) {
        unsigned int* hdst = (unsigned int*)(h_glob + (s & 1) * (BATCH * HDIM));
        const unsigned long long* hsrc =
            (const unsigned long long*)(h_glob + ((s + 1) & 1) * (BATCH * HDIM));

        // ---- (0) device barrier: wait until all wgs finished step s-1 ----
        if (s) {
            if (tid < 64) {
                const unsigned tgt = (unsigned)s;
                for (;;) {
                    unsigned a = __hip_atomic_load(flags + tid,       __ATOMIC_RELAXED, __HIP_MEMORY_SCOPE_AGENT);
                    unsigned b = __hip_atomic_load(flags + tid + 64,  __ATOMIC_RELAXED, __HIP_MEMORY_SCOPE_AGENT);
                    unsigned c = __hip_atomic_load(flags + tid + 128, __ATOMIC_RELAXED, __HIP_MEMORY_SCOPE_AGENT);
                    unsigned d = __hip_atomic_load(flags + tid + 192, __ATOMIC_RELAXED, __HIP_MEMORY_SCOPE_AGENT);
                    if (a >= tgt && b >= tgt && c >= tgt && d >= tgt) break;
                    __builtin_amdgcn_s_sleep(1);
                }
                __builtin_amdgcn_fence(__ATOMIC_ACQUIRE, "agent");
            }
            __syncthreads();
        }

        // ---- (1) issue prev-h loads + gate-precompute load early ----
        float2 g2;
        if (pre)
            g2 = *(const float2*)(gates + ((size_t)s * NROW + Rr) * BATCH + b0);
        unsigned long long hreg[64];
        if (s) {
#pragma unroll
            for (int j = 0; j < 64; j++)
                hreg[j] = __hip_atomic_load(hsrc + tid + TPB * j,
                                            __ATOMIC_RELAXED, __HIP_MEMORY_SCOPE_AGENT);
        }

        float acc0, acc1;
        if (pre) {
            acc0 = bias_r + g2.x;
            acc1 = bias_r + g2.y;
        } else {
            // ---- fallback pass A: stage emb, project (K = 300) ----
            for (int i = tid; i < BATCH * 75; i += TPB) {
                int b = i / 75, j = i - b * 75;
                int row = x[b * SEQL + s];
                float4 v = ((const float4*)(emb + (size_t)row * EDIM))[j];
                *(float4*)&lds[LDSF_H + b * HSTR + 4 * j] = v;
            }
            __syncthreads();
            acc0 = bias_r; acc1 = bias_r;
#pragma unroll 5
            for (int t2 = 0; t2 < 75; t2++) {
                float4 w = wiha[t2], a = hr0[t2], b = hr1[t2];
                acc0 = fmaf(w.x, a.x, acc0); acc0 = fmaf(w.y, a.y, acc0);
                acc0 = fmaf(w.z, a.z, acc0); acc0 = fmaf(w.w, a.w, acc0);
                acc1 = fmaf(w.x, b.x, acc1); acc1 = fmaf(w.y, b.y, acc1);
                acc1 = fmaf(w.z, b.z, acc1); acc1 = fmaf(w.w, b.w, acc1);
            }
            __syncthreads();
        }

        // ---- (2) pass B: recurrent projection (K = 512) ----
        if (s) {
#pragma unroll
            for (int j = 0; j < 64; j++) {
                int idx = tid + TPB * j;
                int b = idx >> 8, kk = idx & 255;
                *(unsigned long long*)&lds[LDSF_H + b * HSTR + 2 * kk] = hreg[j];
            }
            __syncthreads();
#pragma unroll 4
            for (int t2 = 0; t2 < 128; t2++) {
                float4 w = whha[t2], a = hr0[t2], b = hr1[t2];
                acc0 = fmaf(w.x, a.x, acc0); acc0 = fmaf(w.y, a.y, acc0);
                acc0 = fmaf(w.z, a.z, acc0); acc0 = fmaf(w.w, a.w, acc0);
                acc1 = fmaf(w.x, b.x, acc1); acc1 = fmaf(w.y, b.y, acc1);
                acc1 = fmaf(w.z, b.z, acc1); acc1 = fmaf(w.w, b.w, acc1);
            }
            __syncthreads();
        }

        // ---- (3) gate exchange + cell update ----
        lds[r * GSTR + b0] = acc0;
        lds[r * GSTR + b1] = acc1;
        __syncthreads();
        if (cell) {
            float gi = lds[(0 + hi) * GSTR + cb];
            float gf = lds[(2 + hi) * GSTR + cb];
            float gg = lds[(4 + hi) * GSTR + cb];
            float go = lds[(6 + hi) * GSTR + cb];
            float iv = fast_sigmoid(gi);
            float fv = fast_sigmoid(gf);
            float gv = fast_tanh(gg);
            float ov = fast_sigmoid(go);
            c_reg = fv * c_reg + iv * gv;
            float hv = ov * fast_tanh(c_reg);
            __hip_atomic_store(hdst + cb * HDIM + 2 * wg + hi, __float_as_uint(hv),
                               __ATOMIC_RELAXED, __HIP_MEMORY_SCOPE_AGENT);
        }
        __syncthreads();   // all h stores drained (vmcnt 0) before flag release

        // ---- (4) signal step complete ----
        if (tid == 0)
            __hip_atomic_store(flags + wg, (unsigned)(s + 1),
                               __ATOMIC_RELEASE, __HIP_MEMORY_SCOPE_AGENT);
    }
}

// FC head + softmax
extern "C" __global__ void __launch_bounds__(320)
lstm_epilogue(const float* __restrict__ h, const float* __restrict__ W_fc,
              const float* __restrict__ b_fc, float* __restrict__ out)
{
    __shared__ float sl[ODIM * BATCH];
    const int t = threadIdx.x;
    {
        int o = t / BATCH, b = t - o * BATCH;
        float acc = b_fc[o];
        const float4* hv = (const float4*)(h + b * HDIM);
        const float4* wv = (const float4*)(W_fc + o * HDIM);
#pragma unroll 8
        for (int j = 0; j < HDIM / 4; j++) {
            float4 a = hv[j], w = wv[j];
            acc = fmaf(a.x, w.x, acc); acc = fmaf(a.y, w.y, acc);
            acc = fmaf(a.z, w.z, acc); acc = fmaf(a.w, w.w, acc);
        }
        sl[o * BATCH + b] = acc;
    }
    __syncthreads();
    if (t < BATCH) {
        float l0 = sl[t], l1 = sl[BATCH + t], l2 = sl[2 * BATCH + t];
        float l3 = sl[3 * BATCH + t], l4 = sl[4 * BATCH + t];
        float m = fmaxf(fmaxf(fmaxf(l0, l1), fmaxf(l2, l3)), l4);
        float e0 = __expf(l0 - m), e1 = __expf(l1 - m), e2 = __expf(l2 - m);
        float e3 = __expf(l3 - m), e4 = __expf(l4 - m);
        float inv = 1.0f / (e0 + e1 + e2 + e3 + e4);
        out[t * ODIM + 0] = e0 * inv;
        out[t * ODIM + 1] = e1 * inv;
        out[t * ODIM + 2] = e2 * inv;
        out[t * ODIM + 3] = e3 * inv;
        out[t * ODIM + 4] = e4 * inv;
    }
}

extern "C" void kernel_launch(void* const* d_in, const int* in_sizes, int n_in,
                              void* d_out, int out_size, void* d_ws, size_t ws_size,
                              hipStream_t stream)
{
    const int*   x    = (const int*)d_in[0];
    const float* emb  = (const float*)d_in[1];
    const float* W_ih = (const float*)d_in[2];
    const float* W_hh = (const float*)d_in[3];
    const float* b_ih = (const float*)d_in[4];
    const float* b_hh = (const float*)d_in[5];
    const float* W_fc = (const float*)d_in[6];
    const float* b_fc = (const float*)d_in[7];
    float* out = (float*)d_out;

    float* h_glob       = (float*)d_ws;
    unsigned int* flags = (unsigned int*)((char*)d_ws + WS_FLAGS_OFF);
    float* gates        = (float*)((char*)d_ws + WS_GATES_OFF);
    const bool pre = (ws_size >= WS_NEED);

    (void)hipMemsetAsync(flags, 0, WS_FLAGS_BYTES, stream);

    (void)hipFuncSetAttribute((const void*)lstm_persist,
                              hipFuncAttributeMaxDynamicSharedMemorySize, LDS_BYTES);
    if (pre) {
        (void)hipFuncSetAttribute((const void*)lstm_pre,
                                  hipFuncAttributeMaxDynamicSharedMemorySize, PRE_LDS_BYTES);
        lstm_pre<<<SEQL * 8, 256, PRE_LDS_BYTES, stream>>>(x, emb, W_ih, gates);
    }

    lstm_persist<<<NWG, TPB, LDS_BYTES, stream>>>(x, emb, W_ih, W_hh, b_ih, b_hh,
                                                  pre ? gates : nullptr,
                                                  h_glob, flags);
    lstm_epilogue<<<1, 320, 0, stream>>>(h_glob + BATCH * HDIM, W_fc, b_fc, out);
}

// Round 4
// 4088.042 us; speedup vs baseline: 1.6543x; 1.0902x over previous
//
#include <hip/hip_runtime.h>

// ---------------- problem constants ----------------
#define TPB   256
#define NWG   256
#define SEQL  200
#define BATCH 64
#define EDIM  300
#define HDIM  512
#define ODIM  5
#define NROW  (4*HDIM)   // 2048 gate rows

// ---------------- persist-kernel LDS layout (float/word offsets) ----------------
// Region 0 (time-shared): h_T staging [512][64] (k-major, stride 64) /
//                         embT staging [300][64] (fallback) /
//                         gate-exchange ex[16][EX_STR]
#define HT_OFF   0
#define W_OFF    (HDIM * BATCH)            // 32768 words: W_hh rows [8][WHH_STR]
#define WHH_STR  516
#define WIH_OFF  (W_OFF + 8 * WHH_STR)     // fallback W_ih rows [8][WIH_STR]
#define WIH_STR  304
#define EX_STR   72
#define LDS_WORDS (WIH_OFF + 8 * WIH_STR)  // 39328 words
#define LDS_BYTES (LDS_WORDS * 4)          // 157312 B < 160 KiB  (forces 1 wg/CU)

// ---------------- precompute-kernel LDS ----------------
#define ESTR 308
#define PRE_LDS_BYTES (BATCH * ESTR * 4)   // 78848 B

// ---------------- workspace layout ----------------
#define WS_H_FLOATS   (2 * BATCH * HDIM)                    // h_T double buffer
#define WS_FLAGS_OFF  ((size_t)WS_H_FLOATS * 4)
#define WS_FLAGS_BYTES 1024
#define WS_GATES_OFF  (WS_FLAGS_OFF + WS_FLAGS_BYTES)
#define GATES_FLOATS  ((size_t)SEQL * NROW * BATCH)         // 104.9 MB
#define WS_NEED       (WS_GATES_OFF + GATES_FLOATS * 4)

__device__ __forceinline__ float fast_sigmoid(float x) {
    return 1.0f / (1.0f + __expf(-x));
}
__device__ __forceinline__ float fast_tanh(float x) {
    return 2.0f / (1.0f + __expf(-2.0f * x)) - 1.0f;
}

// ============================================================================
// Precompute: gates[s][row][b] = (x_s @ W_ih^T)[b][row]   (no bias)
// ============================================================================
extern "C" __global__ void __launch_bounds__(256, 1)
lstm_pre(const int* __restrict__ x, const float* __restrict__ emb,
         const float* __restrict__ W_ih, float* __restrict__ gates)
{
    extern __shared__ float embs[];
    const int tid = threadIdx.x;
    const int s   = blockIdx.x >> 3;
    const int rb  = blockIdx.x & 7;

    for (int i = tid; i < BATCH * 75; i += 256) {
        int b = i / 75, j = i - b * 75;
        int row = x[b * SEQL + s];
        float4 v = ((const float4*)(emb + (size_t)row * EDIM))[j];
        *(float4*)&embs[b * ESTR + 4 * j] = v;
    }
    __syncthreads();

    const int bi = tid >> 5;
    const int ri = tid & 31;
    const int row0 = rb * 256 + ri * 8;
    const float* wp = W_ih + (size_t)row0 * EDIM;

    float acc[8][8];
#pragma unroll
    for (int a = 0; a < 8; a++)
#pragma unroll
        for (int b = 0; b < 8; b++) acc[a][b] = 0.0f;

    for (int t2 = 0; t2 < 75; t2++) {
        float4 w[8], e[8];
#pragma unroll
        for (int rr = 0; rr < 8; rr++)
            w[rr] = *(const float4*)(wp + rr * EDIM + 4 * t2);
#pragma unroll
        for (int bb = 0; bb < 8; bb++)
            e[bb] = *(const float4*)&embs[(bi * 8 + bb) * ESTR + 4 * t2];
#pragma unroll
        for (int rr = 0; rr < 8; rr++)
#pragma unroll
            for (int bb = 0; bb < 8; bb++) {
                acc[rr][bb] = fmaf(w[rr].x, e[bb].x, acc[rr][bb]);
                acc[rr][bb] = fmaf(w[rr].y, e[bb].y, acc[rr][bb]);
                acc[rr][bb] = fmaf(w[rr].z, e[bb].z, acc[rr][bb]);
                acc[rr][bb] = fmaf(w[rr].w, e[bb].w, acc[rr][bb]);
            }
    }
#pragma unroll
    for (int rr = 0; rr < 8; rr++) {
        float* dst = gates + ((size_t)s * NROW + row0 + rr) * BATCH + bi * 8;
        *(float4*)dst       = make_float4(acc[rr][0], acc[rr][1], acc[rr][2], acc[rr][3]);
        *(float4*)(dst + 4) = make_float4(acc[rr][4], acc[rr][5], acc[rr][6], acc[rr][7]);
    }
}

// ============================================================================
// Persistent LSTM. h exchanged TRANSPOSED: h_T[hidden][batch] so each wg's
// store is 512B contiguous (no partial-line RMW) and loads are coalesced.
// Thread roles: r = gate-row 0..7 (gate g=r>>1, hi=r&1), bq = batch-quad
// 0..15, kh = k-half 0..1. Pass B: h_T float4 = vector operand, W_hh b128
// broadcast. Partials summed via LDS exchange ex[4g+2hi+kh][b].
// ============================================================================
extern "C" __global__ void __launch_bounds__(TPB, 1)
lstm_persist(const int* __restrict__ x, const float* __restrict__ emb,
             const float* __restrict__ W_ih, const float* __restrict__ W_hh,
             const float* __restrict__ b_ih, const float* __restrict__ b_hh,
             const float* __restrict__ gates,   // may be null
             float* __restrict__ h_glob,        // [2][512][64] transposed
             unsigned int* __restrict__ flags)  // [256], memset 0 per launch
{
    extern __shared__ float lds[];
    const int tid = threadIdx.x;
    const int wg  = blockIdx.x;
    const bool pre = (gates != nullptr);

    // ---- stage W_hh rows (8 x 512); W_ih rows only for fallback ----
    for (int i = tid; i < 8 * HDIM; i += TPB) {
        int r = i >> 9, k = i & (HDIM - 1);
        int R = ((r >> 1) << 9) + 2 * wg + (r & 1);
        lds[W_OFF + r * WHH_STR + k] = W_hh[(size_t)R * HDIM + k];
    }
    if (!pre) {
        for (int i = tid; i < 8 * EDIM; i += TPB) {
            int r = i / EDIM, e = i - r * EDIM;
            int R = ((r >> 1) << 9) + 2 * wg + (r & 1);
            lds[WIH_OFF + r * WIH_STR + e] = W_ih[(size_t)R * EDIM + e];
        }
    }

    const int r  = tid & 7;           // gate-row
    const int bq = (tid >> 3) & 15;   // batch quad
    const int kh = tid >> 7;          // k half
    const int Rr = ((r >> 1) << 9) + 2 * wg + (r & 1);
    const float bias_r = b_ih[Rr] + b_hh[Rr];

    const int hi = (tid >> 6) & 1;    // cell role (tid < 128)
    const int cb = tid & 63;
    float c_reg = 0.0f;

    __syncthreads();

    for (int s = 0; s < SEQL; s++) {
        float* hdst = h_glob + (s & 1) * (BATCH * HDIM) + 2 * wg * BATCH;
        const unsigned long long* hsrc =
            (const unsigned long long*)(h_glob + ((s + 1) & 1) * (BATCH * HDIM));

        // ---- (0) prefetch this step's input-proj gates (independent of barrier) ----
        float4 g4 = make_float4(0.f, 0.f, 0.f, 0.f);
        if (pre)
            g4 = *(const float4*)(gates + ((size_t)s * NROW + Rr) * BATCH + 4 * bq);

        float a0 = 0.f, a1 = 0.f, a2 = 0.f, a3 = 0.f;

        // ---- (1) fallback pass A (before barrier: overlaps the wait) ----
        if (!pre) {
            for (int i = tid; i < BATCH * 75; i += TPB) {   // stage embT [e][b]
                int b = i / 75, j = i - b * 75;
                int row = x[b * SEQL + s];
                float4 v = ((const float4*)(emb + (size_t)row * EDIM))[j];
                lds[(4 * j + 0) * BATCH + b] = v.x;
                lds[(4 * j + 1) * BATCH + b] = v.y;
                lds[(4 * j + 2) * BATCH + b] = v.z;
                lds[(4 * j + 3) * BATCH + b] = v.w;
            }
            __syncthreads();
            const int c0 = kh ? 38 : 0, c1 = kh ? 75 : 38;
            const float4* wrow = (const float4*)&lds[WIH_OFF + r * WIH_STR];
            for (int c = c0; c < c1; c++) {
                float4 wv = wrow[c];
                int kb = (4 * c) * BATCH + 4 * bq;
                float4 h0 = *(const float4*)&lds[kb];
                float4 h1 = *(const float4*)&lds[kb + BATCH];
                float4 h2 = *(const float4*)&lds[kb + 2 * BATCH];
                float4 h3 = *(const float4*)&lds[kb + 3 * BATCH];
                a0 = fmaf(wv.x, h0.x, a0); a0 = fmaf(wv.y, h1.x, a0);
                a0 = fmaf(wv.z, h2.x, a0); a0 = fmaf(wv.w, h3.x, a0);
                a1 = fmaf(wv.x, h0.y, a1); a1 = fmaf(wv.y, h1.y, a1);
                a1 = fmaf(wv.z, h2.y, a1); a1 = fmaf(wv.w, h3.y, a1);
                a2 = fmaf(wv.x, h0.z, a2); a2 = fmaf(wv.y, h1.z, a2);
                a2 = fmaf(wv.z, h2.z, a2); a2 = fmaf(wv.w, h3.z, a2);
                a3 = fmaf(wv.x, h0.w, a3); a3 = fmaf(wv.y, h1.w, a3);
                a3 = fmaf(wv.z, h2.w, a3); a3 = fmaf(wv.w, h3.w, a3);
            }
        }

        if (s) {
            // ---- (2) device barrier: all wgs finished step s-1 ----
            if (tid < 64) {
                const unsigned tgt = (unsigned)s;
                for (;;) {
                    unsigned f0 = __hip_atomic_load(flags + tid,       __ATOMIC_RELAXED, __HIP_MEMORY_SCOPE_AGENT);
                    unsigned f1 = __hip_atomic_load(flags + tid + 64,  __ATOMIC_RELAXED, __HIP_MEMORY_SCOPE_AGENT);
                    unsigned f2 = __hip_atomic_load(flags + tid + 128, __ATOMIC_RELAXED, __HIP_MEMORY_SCOPE_AGENT);
                    unsigned f3 = __hip_atomic_load(flags + tid + 192, __ATOMIC_RELAXED, __HIP_MEMORY_SCOPE_AGENT);
                    if (f0 >= tgt && f1 >= tgt && f2 >= tgt && f3 >= tgt) break;
                    __builtin_amdgcn_s_sleep(1);
                }
                __builtin_amdgcn_fence(__ATOMIC_ACQUIRE, "agent");
            }
            __syncthreads();

            // ---- (3) load h_T coalesced; LDS-stage linearly (addr = 8*d bytes) ----
            unsigned long long hreg[64];
#pragma unroll
            for (int j = 0; j < 64; j++)
                hreg[j] = __hip_atomic_load(hsrc + tid + TPB * j,
                                            __ATOMIC_RELAXED, __HIP_MEMORY_SCOPE_AGENT);
#pragma unroll
            for (int j = 0; j < 64; j++)
                *(unsigned long long*)&lds[2 * (tid + TPB * j)] = hreg[j];
            __syncthreads();

            // ---- (4) pass B: h_T float4 vector op, W_hh b128 broadcast ----
            const float4* wrow = (const float4*)&lds[W_OFF + r * WHH_STR + kh * 256];
#pragma unroll 4
            for (int c = 0; c < 64; c++) {
                float4 wv = wrow[c];
                int kb = (kh * 256 + 4 * c) * BATCH + 4 * bq;
                float4 h0 = *(const float4*)&lds[kb];
                float4 h1 = *(const float4*)&lds[kb + BATCH];
                float4 h2 = *(const float4*)&lds[kb + 2 * BATCH];
                float4 h3 = *(const float4*)&lds[kb + 3 * BATCH];
                a0 = fmaf(wv.x, h0.x, a0); a0 = fmaf(wv.y, h1.x, a0);
                a0 = fmaf(wv.z, h2.x, a0); a0 = fmaf(wv.w, h3.x, a0);
                a1 = fmaf(wv.x, h0.y, a1); a1 = fmaf(wv.y, h1.y, a1);
                a1 = fmaf(wv.z, h2.y, a1); a1 = fmaf(wv.w, h3.y, a1);
                a2 = fmaf(wv.x, h0.z, a2); a2 = fmaf(wv.y, h1.z, a2);
                a2 = fmaf(wv.z, h2.z, a2); a2 = fmaf(wv.w, h3.z, a2);
                a3 = fmaf(wv.x, h0.w, a3); a3 = fmaf(wv.y, h1.w, a3);
                a3 = fmaf(wv.z, h2.w, a3); a3 = fmaf(wv.w, h3.w, a3);
            }
        }
        __syncthreads();   // region-0 readers done -> reuse as exchange

        // ---- (5) gate exchange (kh-partials) + cell update ----
        if (kh == 0) {
            a0 += bias_r + g4.x; a1 += bias_r + g4.y;
            a2 += bias_r + g4.z; a3 += bias_r + g4.w;
        }
        *(float4*)&lds[(r * 2 + kh) * EX_STR + 4 * bq] = make_float4(a0, a1, a2, a3);
        __syncthreads();

        if (tid < 128) {
            float gi = lds[(0 + 2*hi) * EX_STR + cb] + lds[(1 + 2*hi) * EX_STR + cb];
            float gf = lds[(4 + 2*hi) * EX_STR + cb] + lds[(5 + 2*hi) * EX_STR + cb];
            float gg = lds[(8 + 2*hi) * EX_STR + cb] + lds[(9 + 2*hi) * EX_STR + cb];
            float go = lds[(12+ 2*hi) * EX_STR + cb] + lds[(13+ 2*hi) * EX_STR + cb];
            float iv = fast_sigmoid(gi);
            float fv = fast_sigmoid(gf);
            float gv = fast_tanh(gg);
            float ov = fast_sigmoid(go);
            c_reg = fv * c_reg + iv * gv;
            float hv = ov * fast_tanh(c_reg);
            // contiguous 512B per wg: h_T[2wg+hi][cb]
            __hip_atomic_store((unsigned int*)hdst + tid, __float_as_uint(hv),
                               __ATOMIC_RELAXED, __HIP_MEMORY_SCOPE_AGENT);
        }
        __syncthreads();   // all stores drained (vmcnt 0) before flag release

        if (tid == 0)
            __hip_atomic_store(flags + wg, (unsigned)(s + 1),
                               __ATOMIC_RELEASE, __HIP_MEMORY_SCOPE_AGENT);
    }
}

// FC head + softmax over TRANSPOSED h_T[512][64]
extern "C" __global__ void __launch_bounds__(320)
lstm_epilogue(const float* __restrict__ hT, const float* __restrict__ W_fc,
              const float* __restrict__ b_fc, float* __restrict__ out)
{
    __shared__ float sl[ODIM * BATCH];
    const int t = threadIdx.x;
    {
        int o = t / BATCH, b = t - o * BATCH;
        float acc = b_fc[o];
        const float4* wv = (const float4*)(W_fc + o * HDIM);
#pragma unroll 8
        for (int k4 = 0; k4 < HDIM / 4; k4++) {
            float4 w = wv[k4];
            acc = fmaf(hT[(4 * k4 + 0) * BATCH + b], w.x, acc);
            acc = fmaf(hT[(4 * k4 + 1) * BATCH + b], w.y, acc);
            acc = fmaf(hT[(4 * k4 + 2) * BATCH + b], w.z, acc);
            acc = fmaf(hT[(4 * k4 + 3) * BATCH + b], w.w, acc);
        }
        sl[o * BATCH + b] = acc;
    }
    __syncthreads();
    if (t < BATCH) {
        float l0 = sl[t], l1 = sl[BATCH + t], l2 = sl[2 * BATCH + t];
        float l3 = sl[3 * BATCH + t], l4 = sl[4 * BATCH + t];
        float m = fmaxf(fmaxf(fmaxf(l0, l1), fmaxf(l2, l3)), l4);
        float e0 = __expf(l0 - m), e1 = __expf(l1 - m), e2 = __expf(l2 - m);
        float e3 = __expf(l3 - m), e4 = __expf(l4 - m);
        float inv = 1.0f / (e0 + e1 + e2 + e3 + e4);
        out[t * ODIM + 0] = e0 * inv;
        out[t * ODIM + 1] = e1 * inv;
        out[t * ODIM + 2] = e2 * inv;
        out[t * ODIM + 3] = e3 * inv;
        out[t * ODIM + 4] = e4 * inv;
    }
}

extern "C" void kernel_launch(void* const* d_in, const int* in_sizes, int n_in,
                              void* d_out, int out_size, void* d_ws, size_t ws_size,
                              hipStream_t stream)
{
    const int*   x    = (const int*)d_in[0];
    const float* emb  = (const float*)d_in[1];
    const float* W_ih = (const float*)d_in[2];
    const float* W_hh = (const float*)d_in[3];
    const float* b_ih = (const float*)d_in[4];
    const float* b_hh = (const float*)d_in[5];
    const float* W_fc = (const float*)d_in[6];
    const float* b_fc = (const float*)d_in[7];
    float* out = (float*)d_out;

    float* h_glob       = (float*)d_ws;
    unsigned int* flags = (unsigned int*)((char*)d_ws + WS_FLAGS_OFF);
    float* gates        = (float*)((char*)d_ws + WS_GATES_OFF);
    const bool pre = (ws_size >= WS_NEED);

    (void)hipMemsetAsync(flags, 0, WS_FLAGS_BYTES, stream);

    (void)hipFuncSetAttribute((const void*)lstm_persist,
                              hipFuncAttributeMaxDynamicSharedMemorySize, LDS_BYTES);
    if (pre) {
        (void)hipFuncSetAttribute((const void*)lstm_pre,
                                  hipFuncAttributeMaxDynamicSharedMemorySize, PRE_LDS_BYTES);
        lstm_pre<<<SEQL * 8, 256, PRE_LDS_BYTES, stream>>>(x, emb, W_ih, gates);
    }

    lstm_persist<<<NWG, TPB, LDS_BYTES, stream>>>(x, emb, W_ih, W_hh, b_ih, b_hh,
                                                  pre ? gates : nullptr,
                                                  h_glob, flags);
    lstm_epilogue<<<1, 320, 0, stream>>>(h_glob + BATCH * HDIM, W_fc, b_fc, out);
}

// Round 5
// 2755.494 us; speedup vs baseline: 2.4544x; 1.4836x over previous
//
#include <hip/hip_runtime.h>

// ---------------- problem constants ----------------
#define TPB   256
#define NWG   256
#define SEQL  200
#define BATCH 64
#define EDIM  300
#define HDIM  512
#define ODIM  5
#define NROW  (4*HDIM)   // 2048 gate rows

// ---------------- persist-kernel LDS layout (word offsets) ----------------
// region0 [0..32768): h_T[512][64] (DMA target) / embT[300][64] (fallback) /
//                     ex[8][64][17] partial-exchange overlay (8704 w)
#define EX_BSTR  17
#define EX_RSTR  (64*EX_BSTR)            // 1088
#define WIH_OFF  32768                   // fallback W_ih rows [8][304]
#define WIH_STR  304
#define LDS_WORDS (WIH_OFF + 8*WIH_STR)  // 35200 words
#define LDS_BYTES (LDS_WORDS*4)          // 140800 B (<160 KiB, forces 1 wg/CU)

#define HBUF_WORDS (BATCH*HDIM)          // 32768 floats = 128 KiB / buffer
#define HBUF_BYTES (HBUF_WORDS*4)

// ---------------- precompute-kernel LDS ----------------
#define ESTR 308
#define PRE_LDS_BYTES (BATCH * ESTR * 4) // 78848 B

#define GATES_FLOATS ((size_t)SEQL * NROW * BATCH)   // 104.9 MB

__device__ __forceinline__ float fast_sigmoid(float x) {
    return 1.0f / (1.0f + __expf(-x));
}
__device__ __forceinline__ float fast_tanh(float x) {
    return 2.0f / (1.0f + __expf(-2.0f * x)) - 1.0f;
}

// 16B global -> LDS DMA (no VGPR round trip)
__device__ __forceinline__ void gll16(const float* g, float* l) {
#if __has_builtin(__builtin_amdgcn_global_load_lds)
    __builtin_amdgcn_global_load_lds(
        (const __attribute__((address_space(1))) unsigned int*)g,
        (__attribute__((address_space(3))) unsigned int*)l, 16, 0, 0);
#else
    *(float4*)l = *(const float4*)g;
#endif
}

// ============================================================================
// Precompute: gates[s][row][b] = (x_s @ W_ih^T)[b][row]   (no bias)
// ============================================================================
extern "C" __global__ void __launch_bounds__(256, 1)
lstm_pre(const int* __restrict__ x, const float* __restrict__ emb,
         const float* __restrict__ W_ih, float* __restrict__ gates)
{
    extern __shared__ float embs[];
    const int tid = threadIdx.x;
    const int s   = blockIdx.x >> 3;
    const int rb  = blockIdx.x & 7;

    for (int i = tid; i < BATCH * 75; i += 256) {
        int b = i / 75, j = i - b * 75;
        int row = x[b * SEQL + s];
        float4 v = ((const float4*)(emb + (size_t)row * EDIM))[j];
        *(float4*)&embs[b * ESTR + 4 * j] = v;
    }
    __syncthreads();

    const int bi = tid >> 5;
    const int ri = tid & 31;
    const int row0 = rb * 256 + ri * 8;
    const float* wp = W_ih + (size_t)row0 * EDIM;

    float acc[8][8];
#pragma unroll
    for (int a = 0; a < 8; a++)
#pragma unroll
        for (int b = 0; b < 8; b++) acc[a][b] = 0.0f;

    for (int t2 = 0; t2 < 75; t2++) {
        float4 w[8], e[8];
#pragma unroll
        for (int rr = 0; rr < 8; rr++)
            w[rr] = *(const float4*)(wp + rr * EDIM + 4 * t2);
#pragma unroll
        for (int bb = 0; bb < 8; bb++)
            e[bb] = *(const float4*)&embs[(bi * 8 + bb) * ESTR + 4 * t2];
#pragma unroll
        for (int rr = 0; rr < 8; rr++)
#pragma unroll
            for (int bb = 0; bb < 8; bb++) {
                acc[rr][bb] = fmaf(w[rr].x, e[bb].x, acc[rr][bb]);
                acc[rr][bb] = fmaf(w[rr].y, e[bb].y, acc[rr][bb]);
                acc[rr][bb] = fmaf(w[rr].z, e[bb].z, acc[rr][bb]);
                acc[rr][bb] = fmaf(w[rr].w, e[bb].w, acc[rr][bb]);
            }
    }
#pragma unroll
    for (int rr = 0; rr < 8; rr++) {
        float* dst = gates + ((size_t)s * NROW + row0 + rr) * BATCH + bi * 8;
        *(float4*)dst       = make_float4(acc[rr][0], acc[rr][1], acc[rr][2], acc[rr][3]);
        *(float4*)(dst + 4) = make_float4(acc[rr][4], acc[rr][5], acc[rr][6], acc[rr][7]);
    }
}

// ============================================================================
// Persistent LSTM. Roles: bo = tid&7 (batch octet), rg = (tid>>3)&1 (rows
// 4rg..4rg+3), kh = tid>>4 (k-slice of 32). W_hh slice lives in 128 VGPRs.
// h_T[512][64] DMA'd to LDS via global_load_lds each step (rotating buffers).
// K-partials summed via ex[row][b][17] LDS exchange -> 128 cell threads.
// ============================================================================
extern "C" __global__ void __launch_bounds__(TPB, 1)
lstm_persist(const int* __restrict__ x, const float* __restrict__ emb,
             const float* __restrict__ W_ih, const float* __restrict__ W_hh,
             const float* __restrict__ b_ih, const float* __restrict__ b_hh,
             const float* __restrict__ gates,   // may be null
             float* __restrict__ hrot,          // rot_n buffers of [512][64]
             int rot_n,
             unsigned int* __restrict__ flags)  // [256], memset 0 per launch
{
    extern __shared__ float lds[];
    const int tid = threadIdx.x;
    const int wg  = blockIdx.x;
    const bool pre = (gates != nullptr);

    const int bo = tid & 7;
    const int rg = (tid >> 3) & 1;
    const int kh = tid >> 4;

    // ---- W_hh slice -> 128 VGPRs: rows 4rg..4rg+3, k in [kh*32, kh*32+32) ----
    float4 w[4][8];
#pragma unroll
    for (int p = 0; p < 4; p++) {
        const int r = 4 * rg + p;                       // local row: g=r>>1, hi=r&1
        const size_t R = (size_t)((r >> 1) * HDIM + 2 * wg + (r & 1));
        const float* wp = W_hh + R * HDIM + kh * 32;
#pragma unroll
        for (int kq = 0; kq < 8; kq++) w[p][kq] = *(const float4*)(wp + 4 * kq);
    }

    // ---- fallback W_ih -> LDS ----
    if (!pre) {
        for (int i = tid; i < 8 * EDIM; i += TPB) {
            int r = i / EDIM, e = i - r * EDIM;
            int R = ((r >> 1) << 9) + 2 * wg + (r & 1);
            lds[WIH_OFF + r * WIH_STR + e] = W_ih[(size_t)R * EDIM + e];
        }
    }

    // cell role: tid<128 owns (hi, cb)
    const int hi = (tid >> 6) & 1;
    const int cb = tid & 63;
    float bias4[4];
#pragma unroll
    for (int g = 0; g < 4; g++) {
        int R = g * HDIM + 2 * wg + hi;
        bias4[g] = b_ih[R] + b_hh[R];
    }
    float c_reg = 0.0f;

    const float* hb = &lds[kh * 2048 + 8 * bo];  // pass-B read base

    int rbuf = 0, wbuf = 1;
    __syncthreads();

    for (int s = 0; s < SEQL; s++) {
        // ---- (0) prefetch this step's input-proj gates (independent of barrier) ----
        float gp[4] = {0.f, 0.f, 0.f, 0.f};
        if (pre && tid < 128) {
#pragma unroll
            for (int g = 0; g < 4; g++)
                gp[g] = gates[((size_t)s * NROW + g * HDIM + 2 * wg + hi) * BATCH + cb];
        }

        float acc[4][8];
#pragma unroll
        for (int p = 0; p < 4; p++)
#pragma unroll
            for (int j = 0; j < 8; j++) acc[p][j] = 0.f;

        // ---- (1) fallback pass A (before the barrier: overlaps the wait) ----
        if (!pre) {
            for (int i = tid; i < BATCH * 75; i += TPB) {   // stage embT [e][b]
                int b = i / 75, j = i - b * 75;
                int row = x[b * SEQL + s];
                float4 v = *(const float4*)(emb + (size_t)row * EDIM + 4 * j);
                lds[(4 * j + 0) * 64 + b] = v.x;
                lds[(4 * j + 1) * 64 + b] = v.y;
                lds[(4 * j + 2) * 64 + b] = v.z;
                lds[(4 * j + 3) * 64 + b] = v.w;
            }
            __syncthreads();
            const int nkq = (kh < 4) ? 16 : ((kh == 4) ? 11 : 0);
            const float* eb = &lds[kh * 4096 + 8 * bo];
            for (int kq = 0; kq < nkq; kq++) {
                float4 wv[4];
#pragma unroll
                for (int p = 0; p < 4; p++)
                    wv[p] = *(const float4*)&lds[WIH_OFF + (4 * rg + p) * WIH_STR + kh * 64 + 4 * kq];
                float4 h0[4], h1[4];
#pragma unroll
                for (int dk = 0; dk < 4; dk++) {
                    h0[dk] = *(const float4*)(eb + (4 * kq + dk) * 64);
                    h1[dk] = *(const float4*)(eb + (4 * kq + dk) * 64 + 4);
                }
#pragma unroll
                for (int p = 0; p < 4; p++) {
#pragma unroll
                    for (int dk = 0; dk < 4; dk++) {
                        float wc = dk == 0 ? wv[p].x : dk == 1 ? wv[p].y : dk == 2 ? wv[p].z : wv[p].w;
                        acc[p][0] = fmaf(wc, h0[dk].x, acc[p][0]);
                        acc[p][1] = fmaf(wc, h0[dk].y, acc[p][1]);
                        acc[p][2] = fmaf(wc, h0[dk].z, acc[p][2]);
                        acc[p][3] = fmaf(wc, h0[dk].w, acc[p][3]);
                        acc[p][4] = fmaf(wc, h1[dk].x, acc[p][4]);
                        acc[p][5] = fmaf(wc, h1[dk].y, acc[p][5]);
                        acc[p][6] = fmaf(wc, h1[dk].z, acc[p][6]);
                        acc[p][7] = fmaf(wc, h1[dk].w, acc[p][7]);
                    }
                }
            }
        }

        if (s) {
            // ---- (2) device barrier: all wgs finished step s-1 ----
            if (tid < 64) {
                const unsigned tgt = (unsigned)s;
                for (;;) {
                    unsigned f0 = __hip_atomic_load(flags + tid,       __ATOMIC_RELAXED, __HIP_MEMORY_SCOPE_AGENT);
                    unsigned f1 = __hip_atomic_load(flags + tid + 64,  __ATOMIC_RELAXED, __HIP_MEMORY_SCOPE_AGENT);
                    unsigned f2 = __hip_atomic_load(flags + tid + 128, __ATOMIC_RELAXED, __HIP_MEMORY_SCOPE_AGENT);
                    unsigned f3 = __hip_atomic_load(flags + tid + 192, __ATOMIC_RELAXED, __HIP_MEMORY_SCOPE_AGENT);
                    if (f0 >= tgt && f1 >= tgt && f2 >= tgt && f3 >= tgt) break;
                    __builtin_amdgcn_s_sleep(1);
                }
                __builtin_amdgcn_fence(__ATOMIC_ACQUIRE, "agent");  // L1+L2 inv
            }
            __syncthreads();

            // ---- (3) h_T -> LDS via global_load_lds (linear, 128 KB) ----
            const float* hs = hrot + (size_t)rbuf * HBUF_WORDS;
#pragma unroll
            for (int c = 0; c < 32; c++)
                gll16(hs + 4 * (tid + 256 * c), &lds[4 * (tid + 256 * c)]);
            __syncthreads();   // drains vmcnt (DMA complete)

            // ---- (4) pass B: W_hh from regs, h from LDS ----
#pragma unroll
            for (int kq = 0; kq < 8; kq++) {
                float4 h0[4], h1[4];
#pragma unroll
                for (int dk = 0; dk < 4; dk++) {
                    h0[dk] = *(const float4*)(hb + (4 * kq + dk) * 64);
                    h1[dk] = *(const float4*)(hb + (4 * kq + dk) * 64 + 4);
                }
#pragma unroll
                for (int p = 0; p < 4; p++) {
                    float4 wv = w[p][kq];
#pragma unroll
                    for (int dk = 0; dk < 4; dk++) {
                        float wc = dk == 0 ? wv.x : dk == 1 ? wv.y : dk == 2 ? wv.z : wv.w;
                        acc[p][0] = fmaf(wc, h0[dk].x, acc[p][0]);
                        acc[p][1] = fmaf(wc, h0[dk].y, acc[p][1]);
                        acc[p][2] = fmaf(wc, h0[dk].z, acc[p][2]);
                        acc[p][3] = fmaf(wc, h0[dk].w, acc[p][3]);
                        acc[p][4] = fmaf(wc, h1[dk].x, acc[p][4]);
                        acc[p][5] = fmaf(wc, h1[dk].y, acc[p][5]);
                        acc[p][6] = fmaf(wc, h1[dk].z, acc[p][6]);
                        acc[p][7] = fmaf(wc, h1[dk].w, acc[p][7]);
                    }
                }
            }
        }
        __syncthreads();   // region0 readers done -> reuse as exchange

        // ---- (5) exchange k-partials: ex[row][b][17] ----
#pragma unroll
        for (int p = 0; p < 4; p++) {
            const int r = 4 * rg + p;
#pragma unroll
            for (int j = 0; j < 8; j++)
                lds[r * EX_RSTR + (8 * bo + j) * EX_BSTR + kh] = acc[p][j];
        }
        __syncthreads();

        // ---- (6) cell update (tid<128 owns (hi, cb)) ----
        if (tid < 128) {
            float gs[4];
#pragma unroll
            for (int g = 0; g < 4; g++) {
                float sum = bias4[g] + gp[g];
#pragma unroll
                for (int kk = 0; kk < 16; kk++)
                    sum += lds[(2 * g + hi) * EX_RSTR + cb * EX_BSTR + kk];
                gs[g] = sum;
            }
            float iv = fast_sigmoid(gs[0]);
            float fv = fast_sigmoid(gs[1]);
            float gv = fast_tanh(gs[2]);
            float ov = fast_sigmoid(gs[3]);
            c_reg = fv * c_reg + iv * gv;
            float hv = ov * fast_tanh(c_reg);
            // contiguous 512B per wg: h_T[2wg+hi][cb]
            unsigned int* hw = (unsigned int*)(hrot + (size_t)wbuf * HBUF_WORDS);
            __hip_atomic_store(hw + 128 * wg + tid, __float_as_uint(hv),
                               __ATOMIC_RELAXED, __HIP_MEMORY_SCOPE_AGENT);
        }
        __syncthreads();   // all h stores drained (vmcnt 0) before flag release

        if (tid == 0)
            __hip_atomic_store(flags + wg, (unsigned)(s + 1),
                               __ATOMIC_RELEASE, __HIP_MEMORY_SCOPE_AGENT);

        rbuf = wbuf;
        wbuf = (wbuf + 1 == rot_n) ? 0 : wbuf + 1;
    }
}

// FC head + softmax over TRANSPOSED h_T[512][64]
extern "C" __global__ void __launch_bounds__(320)
lstm_epilogue(const float* __restrict__ hT, const float* __restrict__ W_fc,
              const float* __restrict__ b_fc, float* __restrict__ out)
{
    __shared__ float sl[ODIM * BATCH];
    const int t = threadIdx.x;
    {
        int o = t / BATCH, b = t - o * BATCH;
        float acc = b_fc[o];
        const float4* wv = (const float4*)(W_fc + o * HDIM);
#pragma unroll 8
        for (int k4 = 0; k4 < HDIM / 4; k4++) {
            float4 w = wv[k4];
            acc = fmaf(hT[(4 * k4 + 0) * BATCH + b], w.x, acc);
            acc = fmaf(hT[(4 * k4 + 1) * BATCH + b], w.y, acc);
            acc = fmaf(hT[(4 * k4 + 2) * BATCH + b], w.z, acc);
            acc = fmaf(hT[(4 * k4 + 3) * BATCH + b], w.w, acc);
        }
        sl[o * BATCH + b] = acc;
    }
    __syncthreads();
    if (t < BATCH) {
        float l0 = sl[t], l1 = sl[BATCH + t], l2 = sl[2 * BATCH + t];
        float l3 = sl[3 * BATCH + t], l4 = sl[4 * BATCH + t];
        float m = fmaxf(fmaxf(fmaxf(l0, l1), fmaxf(l2, l3)), l4);
        float e0 = __expf(l0 - m), e1 = __expf(l1 - m), e2 = __expf(l2 - m);
        float e3 = __expf(l3 - m), e4 = __expf(l4 - m);
        float inv = 1.0f / (e0 + e1 + e2 + e3 + e4);
        out[t * ODIM + 0] = e0 * inv;
        out[t * ODIM + 1] = e1 * inv;
        out[t * ODIM + 2] = e2 * inv;
        out[t * ODIM + 3] = e3 * inv;
        out[t * ODIM + 4] = e4 * inv;
    }
}

extern "C" void kernel_launch(void* const* d_in, const int* in_sizes, int n_in,
                              void* d_out, int out_size, void* d_ws, size_t ws_size,
                              hipStream_t stream)
{
    const int*   x    = (const int*)d_in[0];
    const float* emb  = (const float*)d_in[1];
    const float* W_ih = (const float*)d_in[2];
    const float* W_hh = (const float*)d_in[3];
    const float* b_ih = (const float*)d_in[4];
    const float* b_hh = (const float*)d_in[5];
    const float* W_fc = (const float*)d_in[6];
    const float* b_fc = (const float*)d_in[7];
    float* out = (float*)d_out;

    // ws layout: [flags 1KB][gates (optional)][rotating h buffers]
    unsigned int* flags = (unsigned int*)d_ws;
    char* p = (char*)d_ws + 1024;
    size_t remain = (ws_size > 1024) ? ws_size - 1024 : 0;
    const size_t gates_bytes = GATES_FLOATS * sizeof(float);
    float* gates = nullptr;
    if (remain >= gates_bytes + 2 * (size_t)HBUF_BYTES) {
        gates = (float*)p;
        p += gates_bytes;
        remain -= gates_bytes;
    }
    int rot_n = (int)(remain / HBUF_BYTES);
    if (rot_n > SEQL + 1) rot_n = SEQL + 1;
    if (rot_n < 2) rot_n = 2;
    float* hrot = (float*)p;

    (void)hipMemsetAsync(flags, 0, 1024, stream);

    (void)hipFuncSetAttribute((const void*)lstm_persist,
                              hipFuncAttributeMaxDynamicSharedMemorySize, LDS_BYTES);
    if (gates) {
        (void)hipFuncSetAttribute((const void*)lstm_pre,
                                  hipFuncAttributeMaxDynamicSharedMemorySize, PRE_LDS_BYTES);
        lstm_pre<<<SEQL * 8, 256, PRE_LDS_BYTES, stream>>>(x, emb, W_ih, gates);
    }

    lstm_persist<<<NWG, TPB, LDS_BYTES, stream>>>(x, emb, W_ih, W_hh, b_ih, b_hh,
                                                  gates, hrot, rot_n, flags);

    const int fin = SEQL % rot_n;   // buffer written at step SEQL-1
    lstm_epilogue<<<1, 320, 0, stream>>>(hrot + (size_t)fin * HBUF_WORDS,
                                         W_fc, b_fc, out);
}